// Round 1
// baseline (1124.132 us; speedup 1.0000x reference)
//
#include <hip/hip_runtime.h>
#include <stdint.h>

#define BB 64
#define TT 2048
#define KK 128
#define QSTRIDE 40   // fallback kernel: banks {0,8,16,24}+4j -> conflict-free

typedef float f32x16 __attribute__((ext_vector_type(16)));
typedef float f32x2  __attribute__((ext_vector_type(2)));

__device__ __forceinline__ float waveMax(float v) {
#pragma unroll
    for (int off = 32; off; off >>= 1) v = fmaxf(v, __shfl_xor(v, off, 64));
    return v;
}
__device__ __forceinline__ float waveSum(float v) {
#pragma unroll
    for (int off = 32; off; off >>= 1) v += __shfl_xor(v, off, 64);
    return v;
}
__device__ __forceinline__ int waveSumI(int v) {
#pragma unroll
    for (int off = 32; off; off >>= 1) v += __shfl_xor(v, off, 64);
    return v;
}
// quad reduction via DPP quad_perm (VALU-speed; replaces 2 ds_bpermute)
__device__ __forceinline__ float quadSum(float s) {
    int x = __builtin_amdgcn_mov_dpp(__float_as_int(s), 0xB1, 0xf, 0xf, true); // xor1
    s += __int_as_float(x);
    x = __builtin_amdgcn_mov_dpp(__float_as_int(s), 0x4E, 0xf, 0xf, true);     // xor2
    s += __int_as_float(x);
    return s;
}
__device__ __forceinline__ float waveMaxFast(float v) {
    int x = __builtin_amdgcn_mov_dpp(__float_as_int(v), 0xB1, 0xf, 0xf, true);
    v = fmaxf(v, __int_as_float(x));
    x = __builtin_amdgcn_mov_dpp(__float_as_int(v), 0x4E, 0xf, 0xf, true);
    v = fmaxf(v, __int_as_float(x));
#pragma unroll
    for (int off = 4; off <= 32; off <<= 1) v = fmaxf(v, __shfl_xor(v, off, 64));
    return v;
}

// ---- DPP primitives (all-VALU, no DS pipe) ----
template<int C> __device__ __forceinline__ float dppMax(float v) {
    int x = __builtin_amdgcn_mov_dpp(__float_as_int(v), C, 0xf, 0xf, true);
    return fmaxf(v, __int_as_float(x));
}
template<int C> __device__ __forceinline__ float dppAdd(float v) {
    int x = __builtin_amdgcn_mov_dpp(__float_as_int(v), C, 0xf, 0xf, true);
    return v + __int_as_float(x);
}
// full sum across each 16-lane row: xor1, xor2 (quad_perm), ror4, ror8
__device__ __forceinline__ float red16(float s) {
    s = dppAdd<0xB1>(s);    // quad_perm xor1
    s = dppAdd<0x4E>(s);    // quad_perm xor2
    s = dppAdd<0x124>(s);   // row_ror:4
    s = dppAdd<0x128>(s);   // row_ror:8
    return s;
}
// wave max; result valid in lanes 32..63 (write from lane 63). All-DPP.
__device__ __forceinline__ float waveMaxTo63(float v) {
    v = dppMax<0xB1>(v);
    v = dppMax<0x4E>(v);
    v = dppMax<0x124>(v);
    v = dppMax<0x128>(v);   // each 16-row now holds row-max replicated
    v = dppMax<0x142>(v);   // row_bcast15
    v = dppMax<0x143>(v);   // row_bcast31 -> lanes 32..63 = full max
    return v;
}

// lgkm-only barrier: LDS visibility without draining global prefetch (vmcnt).
__device__ __forceinline__ void lds_barrier() {
    asm volatile("s_waitcnt lgkmcnt(0)\n\ts_barrier" ::: "memory");
}

#define PKFMA(ep, wp, acc) acc = __builtin_elementwise_fma(ep, wp, acc)

#define MATVEC_QUARTER(Wa, Wb, ev, sOut) {                          \
    const float4 e0 = ev[0], e1 = ev[1], e2 = ev[2], e3 = ev[3];    \
    const float4 e4 = ev[4], e5 = ev[5], e6 = ev[6], e7 = ev[7];    \
    f32x2 a0 = {0.f,0.f}, a1 = {0.f,0.f}, a2 = {0.f,0.f}, a3 = {0.f,0.f}; \
    PKFMA(((f32x2){e0.x, e0.y}), ((f32x2){Wa[0],  Wa[1]}),  a0);    \
    PKFMA(((f32x2){e0.z, e0.w}), ((f32x2){Wa[2],  Wa[3]}),  a1);    \
    PKFMA(((f32x2){e1.x, e1.y}), ((f32x2){Wa[4],  Wa[5]}),  a2);    \
    PKFMA(((f32x2){e1.z, e1.w}), ((f32x2){Wa[6],  Wa[7]}),  a3);    \
    PKFMA(((f32x2){e2.x, e2.y}), ((f32x2){Wa[8],  Wa[9]}),  a0);    \
    PKFMA(((f32x2){e2.z, e2.w}), ((f32x2){Wa[10], Wa[11]}), a1);    \
    PKFMA(((f32x2){e3.x, e3.y}), ((f32x2){Wa[12], Wa[13]}), a2);    \
    PKFMA(((f32x2){e3.z, e3.w}), ((f32x2){Wa[14], Wa[15]}), a3);    \
    PKFMA(((f32x2){e4.x, e4.y}), ((f32x2){Wb[0],  Wb[1]}),  a0);    \
    PKFMA(((f32x2){e4.z, e4.w}), ((f32x2){Wb[2],  Wb[3]}),  a1);    \
    PKFMA(((f32x2){e5.x, e5.y}), ((f32x2){Wb[4],  Wb[5]}),  a2);    \
    PKFMA(((f32x2){e5.z, e5.w}), ((f32x2){Wb[6],  Wb[7]}),  a3);    \
    PKFMA(((f32x2){e6.x, e6.y}), ((f32x2){Wb[8],  Wb[9]}),  a0);    \
    PKFMA(((f32x2){e6.z, e6.w}), ((f32x2){Wb[10], Wb[11]}), a1);    \
    PKFMA(((f32x2){e7.x, e7.y}), ((f32x2){Wb[12], Wb[13]}), a2);    \
    PKFMA(((f32x2){e7.z, e7.w}), ((f32x2){Wb[14], Wb[15]}), a3);    \
    const f32x2 s2 = (a0 + a1) + (a2 + a3);                         \
    sOut = s2[0] + s2[1]; }

// Forward/backward meet-in-the-middle (proven). NEW in this round: thread
// repartition of the 128x128 matvec from (4 threads/output, 32 inputs each)
// to (R=4 outputs x C=8 inputs per thread). Same 16 pk-FMA/thread, but DS
// reads drop 4x (64 -> 16 ds_read_b128 per step per CU); the 16-lane partial
// reduction per output is all-DPP (quad_perm + row_ror), and the renorm
// broadcast paths are DPP-only too. Per-step cost was shown ~proportional to
// DS instruction count; this cuts it ~3.3x.
//
// Thread map: G = tid>>4 in [0,32) owns outputs k0=4G..4G+3 (replicated over
// ig = tid&15); ig covers inputs 8*ig..8*ig+7.
// e layout: chunk c (8 floats) at word c*8 + (c>>2)*4  -> 16B-aligned b128
// reads, 16 distinct addrs spread 2-per-bank (2-way = free), 4 output-groups
// broadcast the same addresses.
extern "C" __global__ __launch_bounds__(512)
void crf_fb_kernel(const float* __restrict__ em,
                   const int* __restrict__ mask,
                   const int* __restrict__ tgt,
                   const float* __restrict__ trans,
                   const float* __restrict__ start,
                   const int* __restrict__ forb,
                   float* __restrict__ ef,      // [128][KK] forward exp-alpha
                   float* __restrict__ db,      // [128][KK] backward exp-beta
                   float* __restrict__ Mfb)     // [256] scales: fwd 0..127, bwd 128..255
{
    const int tid  = threadIdx.x;
    const int G    = tid >> 4;          // output group: outputs 4G..4G+3
    const int ig   = tid & 15;          // input chunk: inputs 8ig..8ig+7
    const int k0   = G << 2;
    const int i0   = ig << 3;
    const int w    = tid >> 6;
    const int lane = tid & 63;
    const bool fwdDir = (blockIdx.x < 2 * BB);
    const int c    = blockIdx.x & (2 * BB - 1);
    const int b    = c & (BB - 1);
    const bool sup = (c < BB);

    __shared__ __align__(16) float eLDS[2][144]; // swizzled: chunk c at c*8+(c>>2)*4
    __shared__ float wmLDS[8];
    __shared__ float redLDS[8];
    __shared__ int lenLDS;

    // ---- length ----
    if (tid == 0) lenLDS = 0;
    const int4 m4 = ((const int4*)(mask + (size_t)b * TT))[tid];
    int ps = m4.x + m4.y + m4.z + m4.w;
    ps = waveSumI(ps);
    __syncthreads();
    if (lane == 0) atomicAdd(&lenLDS, ps);

    const float4 st4 = *(const float4*)(start + k0);
    const float* __restrict__ emrow = em + (size_t)b * TT * KK;
    const int* __restrict__ trow = tgt + (size_t)b * TT * KK;

    // ---- W block: outputs 4G..4G+3 x inputs 8ig..8ig+7 ----
    float Wv[4][8];
    if (fwdDir) {
#pragma unroll
        for (int r = 0; r < 4; ++r)
#pragma unroll
            for (int j = 0; j < 8; ++j) {
                const int idx = (i0 + j) * KK + (k0 + r);
                Wv[r][j] = forb[idx] ? 0.0f : __expf(trans[idx]);
            }
    } else {
#pragma unroll
        for (int r = 0; r < 4; ++r)
#pragma unroll
            for (int j = 0; j < 8; ++j) {
                const int idx = (k0 + r) * KK + (i0 + j);
                Wv[r][j] = forb[idx] ? 0.0f : __expf(trans[idx]);
            }
    }
    __syncthreads();                     // lenLDS ready
    const int len = lenLDS;              // uniform, in [1024, 2048]
    const int mid = len >> 1;
    const int N   = fwdDir ? mid : (len - 1 - mid);   // serial steps (>=511)
    const int t0  = fwdDir ? 0 : (len - 1);

    // LDS word offsets
    const int rb = i0 + ((ig >> 2) << 2);                 // read base (chunk ig)
    const int cw = G >> 1;                                // write chunk
    const int wb = (cw << 3) + ((cw >> 2) << 2) + ((G & 1) << 2);

    // ---- init vector at t0: exact max renorm ----
    float4 v0 = *(const float4*)(emrow + (size_t)t0 * KK + k0);
    if (sup) {
        const int4 t4 = *(const int4*)(trow + (size_t)t0 * KK + k0);
        v0.x = t4.x ? v0.x : -100000.0f;
        v0.y = t4.y ? v0.y : -100000.0f;
        v0.z = t4.z ? v0.z : -100000.0f;
        v0.w = t4.w ? v0.w : -100000.0f;
    }
    v0.x += st4.x; v0.y += st4.y; v0.z += st4.z; v0.w += st4.w;
    const float vmax = fmaxf(fmaxf(v0.x, v0.y), fmaxf(v0.z, v0.w));
    const float wm0 = waveMax(vmax);
    if (lane == 0) redLDS[w] = wm0;
    __syncthreads();
    float M0 = fmaxf(fmaxf(fmaxf(redLDS[0], redLDS[1]), fmaxf(redLDS[2], redLDS[3])),
                     fmaxf(fmaxf(redLDS[4], redLDS[5]), fmaxf(redLDS[6], redLDS[7])));
    double M = (double)M0;
    float4 eNewV;
    eNewV.x = __expf(v0.x - M0);
    eNewV.y = __expf(v0.y - M0);
    eNewV.z = __expf(v0.z - M0);
    eNewV.w = __expf(v0.w - M0);
    if (ig == 0) *(float4*)&eLDS[0][wb] = eNewV;

    // iter n consumes bi[time]: fwd time=n; bwd time=len-1-n except the final
    // bwd iter which must NOT apply bi_mid (forward already owns it) -> bi:=0.
    auto loadBi = [&](int n) -> float4 {
        if (n > N || (!fwdDir && n == N)) return make_float4(0.f, 0.f, 0.f, 0.f);
        const int t = fwdDir ? n : (len - 1 - n);
        float4 e4 = *(const float4*)(emrow + (size_t)t * KK + k0);
        if (sup) {
            const int4 t4 = *(const int4*)(trow + (size_t)t * KK + k0);
            e4.x = t4.x ? e4.x : -100000.0f;
            e4.y = t4.y ? e4.y : -100000.0f;
            e4.z = t4.z ? e4.z : -100000.0f;
            e4.w = t4.w ? e4.w : -100000.0f;
        }
        e4.x += st4.x; e4.y += st4.y; e4.z += st4.z; e4.w += st4.w;
        return e4;
    };

    float4 biA = loadBi(1), biB = loadBi(2), biC = loadBi(3), biD = loadBi(4);
    lds_barrier();                       // publish eLDS[0]

#define FMA8(ar, Wr) {                                              \
    PKFMA(((f32x2){e0.x, e0.y}), ((f32x2){Wr[0], Wr[1]}), ar);      \
    PKFMA(((f32x2){e0.z, e0.w}), ((f32x2){Wr[2], Wr[3]}), ar);      \
    PKFMA(((f32x2){e1.x, e1.y}), ((f32x2){Wr[4], Wr[5]}), ar);      \
    PKFMA(((f32x2){e1.z, e1.w}), ((f32x2){Wr[6], Wr[7]}), ar); }

#pragma unroll 4
    for (int n = 1; n <= N; ++n) {
        const int p = (n - 1) & 1;
        const float4 biN = loadBi(n + 4); // rides across lgkm-only barriers

        // block-renorm (proven): measure at n%4==3 (from prev step's eNew =
        // s*exp(ba), so log(eNew) == log(s)+ba; -inf for dead states: ok),
        // apply at n%4==0. All-DPP reductions; 1 DS write + 1 DS read per wave.
        if ((n & 3) == 3) {
            const float mprev = fmaxf(fmaxf(eNewV.x, eNewV.y), fmaxf(eNewV.z, eNewV.w));
            const float u = waveMaxTo63(__logf(mprev));
            if (lane == 63) wmLDS[w] = u;
        }
        float r = 0.0f;
        if ((n & 3) == 0) {
            float rv = wmLDS[lane & 7];   // 8 distinct banks, broadcast: 1 DS instr
            rv = dppMax<0xB1>(rv);
            rv = dppMax<0x4E>(rv);
            rv = dppMax<0x124>(rv);       // all lanes now hold max(wmLDS[0..7])
            r = rv;
            M += (double)r;
        }
        const float f0 = __expf(biA.x - r);   // off critical path (early)
        const float f1 = __expf(biA.y - r);
        const float f2 = __expf(biA.z - r);
        const float f3 = __expf(biA.w - r);

        const float4* __restrict__ ev = (const float4*)&eLDS[p][rb];
        const float4 e0 = ev[0], e1 = ev[1];

        f32x2 a0 = {0.f,0.f}, a1 = {0.f,0.f}, a2 = {0.f,0.f}, a3 = {0.f,0.f};
        FMA8(a0, Wv[0]); FMA8(a1, Wv[1]); FMA8(a2, Wv[2]); FMA8(a3, Wv[3]);
        float s0 = a0[0] + a0[1];
        float s1 = a1[0] + a1[1];
        float s2 = a2[0] + a2[1];
        float s3 = a3[0] + a3[1];
        s0 = red16(s0); s1 = red16(s1); s2 = red16(s2); s3 = red16(s3);

        eNewV.x = s0 * f0; eNewV.y = s1 * f1; eNewV.z = s2 * f2; eNewV.w = s3 * f3;
        if (ig == 0) *(float4*)&eLDS[p ^ 1][wb] = eNewV;

        biA = biB; biB = biC; biC = biD; biD = biN;
        lds_barrier();                   // single barrier/step, lgkm-only
    }

    if (ig == 0) *(float4*)((fwdDir ? ef : db) + (size_t)c * KK + k0) = eNewV;
    if (tid == 0) Mfb[(fwdDir ? 0 : 2 * BB) + c] = (float)M;
}

// z[c] = Mf[c] + Mb[c] + log(dot(ef[c], db[c])); out[b] = z[b] - z[b+64]
extern "C" __global__ void crf_combine_kernel(const float* __restrict__ ef,
                                              const float* __restrict__ db,
                                              const float* __restrict__ Mfb,
                                              float* __restrict__ out)
{
    const int b = blockIdx.x;
    const int tid = threadIdx.x;         // 0..127 = state
    const int wv = tid >> 6, lane = tid & 63;
    __shared__ float red[2][2];
    __shared__ float z[2];
#pragma unroll
    for (int s = 0; s < 2; ++s) {
        const int c = b + s * BB;
        const float v = ef[(size_t)c * KK + tid] * db[(size_t)c * KK + tid];
        const float p = waveSum(v);
        if (lane == 0) red[s][wv] = p;
    }
    __syncthreads();
    if (tid < 2) {
        const int c = b + tid * BB;
        z[tid] = Mfb[c] + Mfb[2 * BB + c] + __logf(red[tid][0] + red[tid][1]);
    }
    __syncthreads();
    if (tid == 0) out[b] = z[0] - z[1];
}

// ---------------- fallback (R8, proven): used only if ws is too small -------
extern "C" __global__ __launch_bounds__(512)
__attribute__((amdgpu_waves_per_eu(2, 2)))
void crf_chain_kernel(const float* __restrict__ em, const int* __restrict__ mask,
                      const int* __restrict__ tgt, const float* __restrict__ trans,
                      const float* __restrict__ start, const int* __restrict__ forb,
                      float* __restrict__ zbuf)
{
    const int tid = threadIdx.x;
    const int k = tid >> 2, q = tid & 3, w = tid >> 6, lane = tid & 63;
    const int c = blockIdx.x, b = c & (BB - 1);
    const bool sup = (c < BB);
    __shared__ __align__(16) float eLDS[2][KK];
    __shared__ float wmLDS[8];
    __shared__ float redLDS[8];
    __shared__ int lenLDS;
    if (tid == 0) lenLDS = 0;
    const int4 m4 = ((const int4*)(mask + (size_t)b * TT))[tid];
    int ps = m4.x + m4.y + m4.z + m4.w;
    ps = waveSumI(ps);
    __syncthreads();
    if (lane == 0) atomicAdd(&lenLDS, ps);
    const float st = start[k];
    const float* __restrict__ emrow = em + (size_t)b * TT * KK;
    const int* __restrict__ trow = tgt + (size_t)b * TT * KK;
    const int ib = q * 32;
    f32x16 Wa, Wb;
#pragma unroll
    for (int j = 0; j < 16; ++j) {
        Wa[j] = forb[(ib + j     ) * KK + k] ? 0.0f : __expf(trans[(ib + j     ) * KK + k]);
        Wb[j] = forb[(ib + 16 + j) * KK + k] ? 0.0f : __expf(trans[(ib + 16 + j) * KK + k]);
    }
    float v0 = emrow[k];
    if (sup && !trow[k]) v0 = -100000.0f;
    v0 += st;
    const float wm0 = waveMax(v0);
    if (lane == 0) redLDS[w] = wm0;
    __syncthreads();
    const int len = lenLDS;
    float M0 = fmaxf(fmaxf(fmaxf(redLDS[0], redLDS[1]), fmaxf(redLDS[2], redLDS[3])),
                     fmaxf(fmaxf(redLDS[4], redLDS[5]), fmaxf(redLDS[6], redLDS[7])));
    double M = (double)M0;
    float eNew = __expf(v0 - M0);
    if (q == 0) eLDS[0][k] = eNew;
    auto bival = [&](int t) -> float {
        float e0 = emrow[(size_t)t * KK + k];
        if (sup) { if (!trow[(size_t)t * KK + k]) e0 = -100000.0f; }
        return e0 + st;
    };
    float biA = (len > 1) ? bival(1) : 0.0f;
    float biB = (len > 2) ? bival(2) : 0.0f;
    float biC = (len > 3) ? bival(3) : 0.0f;
    float biD = (len > 4) ? bival(4) : 0.0f;
    float sPrev = 1.0f, baPrev = 0.0f;
    lds_barrier();
#pragma unroll 4
    for (int t = 1; t < len; ++t) {
        const int p = (t - 1) & 1;
        const float biN = (t + 4 < len) ? bival(t + 4) : 0.0f;
        if ((t & 3) == 3) {
            const float u = __logf(sPrev) + baPrev;
            const float wmx = waveMaxFast(u);
            if (lane == 0) wmLDS[w] = wmx;
        }
        float r = 0.0f;
        if ((t & 3) == 0) {
            r = fmaxf(fmaxf(fmaxf(wmLDS[0], wmLDS[1]), fmaxf(wmLDS[2], wmLDS[3])),
                      fmaxf(fmaxf(wmLDS[4], wmLDS[5]), fmaxf(wmLDS[6], wmLDS[7])));
            M += (double)r;
        }
        const float ba = biA - r;
        const float f = __expf(ba);
        const float4* __restrict__ ev = (const float4*)eLDS[p] + q * 8;
        float s;
        MATVEC_QUARTER(Wa, Wb, ev, s)
        s = quadSum(s);
        eNew = s * f;
        if (q == 0) eLDS[p ^ 1][k] = eNew;
        sPrev = s; baPrev = ba;
        biA = biB; biB = biC; biC = biD; biD = biN;
        lds_barrier();
    }
    const float sm = waveSum((q == 0) ? eNew : 0.0f);
    if (lane == 0) redLDS[w] = sm;
    __syncthreads();
    if (tid == 0) {
        const float ss = ((redLDS[0] + redLDS[1]) + (redLDS[2] + redLDS[3]))
                       + ((redLDS[4] + redLDS[5]) + (redLDS[6] + redLDS[7]));
        zbuf[c] = (float)(M + (double)__logf(ss));
    }
}

extern "C" __global__ void crf_final_kernel(const float* __restrict__ z,
                                            float* __restrict__ out)
{
    const int b = threadIdx.x;
    out[b] = z[b] - z[b + BB];
}

extern "C" void kernel_launch(void* const* d_in, const int* in_sizes, int n_in,
                              void* d_out, int out_size, void* d_ws, size_t ws_size,
                              hipStream_t stream) {
    const float* em    = (const float*)d_in[0];
    const int*   mask  = (const int*)d_in[1];
    const int*   tgt   = (const int*)d_in[2];
    const float* trans = (const float*)d_in[3];
    const float* start = (const float*)d_in[4];
    const int*   forb  = (const int*)d_in[5];

    const size_t need = (size_t)(2 * 2 * BB * KK + 4 * BB) * sizeof(float); // 132 KB
    if (ws_size >= need) {
        float* ef  = (float*)d_ws;                       // [128][128]
        float* db  = ef + 2 * BB * KK;                   // [128][128]
        float* Mfb = db + 2 * BB * KK;                   // [256]
        crf_fb_kernel<<<4 * BB, 512, 0, stream>>>(em, mask, tgt, trans, start,
                                                  forb, ef, db, Mfb);
        crf_combine_kernel<<<BB, 128, 0, stream>>>(ef, db, Mfb, (float*)d_out);
    } else {
        float* zbuf = (float*)d_ws;
        crf_chain_kernel<<<2 * BB, 512, 0, stream>>>(em, mask, tgt, trans, start,
                                                     forb, zbuf);
        crf_final_kernel<<<1, BB, 0, stream>>>(zbuf, (float*)d_out);
    }
}

// Round 2
// 1115.300 us; speedup vs baseline: 1.0079x; 1.0079x over previous
//
#include <hip/hip_runtime.h>
#include <stdint.h>

#define BB 64
#define TT 2048
#define KK 128

typedef float f32x16 __attribute__((ext_vector_type(16)));
typedef float f32x2  __attribute__((ext_vector_type(2)));

__device__ __forceinline__ float waveMax(float v) {
#pragma unroll
    for (int off = 32; off; off >>= 1) v = fmaxf(v, __shfl_xor(v, off, 64));
    return v;
}
__device__ __forceinline__ float waveSum(float v) {
#pragma unroll
    for (int off = 32; off; off >>= 1) v += __shfl_xor(v, off, 64);
    return v;
}
__device__ __forceinline__ int waveSumI(int v) {
#pragma unroll
    for (int off = 32; off; off >>= 1) v += __shfl_xor(v, off, 64);
    return v;
}
// quad reduction via DPP quad_perm (VALU-speed; replaces 2 ds_bpermute)
__device__ __forceinline__ float quadSum(float s) {
    int x = __builtin_amdgcn_mov_dpp(__float_as_int(s), 0xB1, 0xf, 0xf, true); // xor1
    s += __int_as_float(x);
    x = __builtin_amdgcn_mov_dpp(__float_as_int(s), 0x4E, 0xf, 0xf, true);     // xor2
    s += __int_as_float(x);
    return s;
}
__device__ __forceinline__ float waveMaxFast(float v) {
    int x = __builtin_amdgcn_mov_dpp(__float_as_int(v), 0xB1, 0xf, 0xf, true);
    v = fmaxf(v, __int_as_float(x));
    x = __builtin_amdgcn_mov_dpp(__float_as_int(v), 0x4E, 0xf, 0xf, true);
    v = fmaxf(v, __int_as_float(x));
#pragma unroll
    for (int off = 4; off <= 32; off <<= 1) v = fmaxf(v, __shfl_xor(v, off, 64));
    return v;
}

// ---- DPP primitives (all-VALU, no DS pipe) ----
template<int C> __device__ __forceinline__ float dppMax(float v) {
    int x = __builtin_amdgcn_mov_dpp(__float_as_int(v), C, 0xf, 0xf, true);
    return fmaxf(v, __int_as_float(x));
}
// wave max; result valid in lanes 32..63 (write from lane 63). All-DPP.
__device__ __forceinline__ float waveMaxTo63(float v) {
    v = dppMax<0xB1>(v);
    v = dppMax<0x4E>(v);
    v = dppMax<0x124>(v);
    v = dppMax<0x128>(v);   // each 16-row now holds row-max replicated
    v = dppMax<0x142>(v);   // row_bcast15
    v = dppMax<0x143>(v);   // row_bcast31 -> lanes 32..63 = full max
    return v;
}

// lgkm-only barrier: LDS visibility without draining global prefetch (vmcnt).
__device__ __forceinline__ void lds_barrier() {
    asm volatile("s_waitcnt lgkmcnt(0)\n\ts_barrier" ::: "memory");
}

#define PKFMA(ep, wp, acc) acc = __builtin_elementwise_fma(ep, wp, acc)

#define MATVEC_QUARTER(Wa, Wb, ev, sOut) {                          \
    const float4 e0 = ev[0], e1 = ev[1], e2 = ev[2], e3 = ev[3];    \
    const float4 e4 = ev[4], e5 = ev[5], e6 = ev[6], e7 = ev[7];    \
    f32x2 a0 = {0.f,0.f}, a1 = {0.f,0.f}, a2 = {0.f,0.f}, a3 = {0.f,0.f}; \
    PKFMA(((f32x2){e0.x, e0.y}), ((f32x2){Wa[0],  Wa[1]}),  a0);    \
    PKFMA(((f32x2){e0.z, e0.w}), ((f32x2){Wa[2],  Wa[3]}),  a1);    \
    PKFMA(((f32x2){e1.x, e1.y}), ((f32x2){Wa[4],  Wa[5]}),  a2);    \
    PKFMA(((f32x2){e1.z, e1.w}), ((f32x2){Wa[6],  Wa[7]}),  a3);    \
    PKFMA(((f32x2){e2.x, e2.y}), ((f32x2){Wa[8],  Wa[9]}),  a0);    \
    PKFMA(((f32x2){e2.z, e2.w}), ((f32x2){Wa[10], Wa[11]}), a1);    \
    PKFMA(((f32x2){e3.x, e3.y}), ((f32x2){Wa[12], Wa[13]}), a2);    \
    PKFMA(((f32x2){e3.z, e3.w}), ((f32x2){Wa[14], Wa[15]}), a3);    \
    PKFMA(((f32x2){e4.x, e4.y}), ((f32x2){Wb[0],  Wb[1]}),  a0);    \
    PKFMA(((f32x2){e4.z, e4.w}), ((f32x2){Wb[2],  Wb[3]}),  a1);    \
    PKFMA(((f32x2){e5.x, e5.y}), ((f32x2){Wb[4],  Wb[5]}),  a2);    \
    PKFMA(((f32x2){e5.z, e5.w}), ((f32x2){Wb[6],  Wb[7]}),  a3);    \
    PKFMA(((f32x2){e6.x, e6.y}), ((f32x2){Wb[8],  Wb[9]}),  a0);    \
    PKFMA(((f32x2){e6.z, e6.w}), ((f32x2){Wb[10], Wb[11]}), a1);    \
    PKFMA(((f32x2){e7.x, e7.y}), ((f32x2){Wb[12], Wb[13]}), a2);    \
    PKFMA(((f32x2){e7.z, e7.w}), ((f32x2){Wb[14], Wb[15]}), a3);    \
    const f32x2 s2 = (a0 + a1) + (a2 + a3);                         \
    sOut = s2[0] + s2[1]; }

// Forward/backward meet-in-the-middle (proven structure). NEW this round:
// 2-wave blocks with W held ENTIRELY in registers. Each of 128 threads owns
// one output state k; its W column (fwd) / row (bwd) lives in 64 f32x2 VGPRs.
// Per step each thread computes the full 128-MAC dot product (64 v_pk_fma_f32)
// reading e via lane-UNIFORM broadcast ds_read_b128 (32 reads, conflict-free),
// then writes 1 float. No cross-lane reduction at all; the barrier syncs only
// 2 waves (vs 8). Rationale: R1 showed per-step time is NOT proportional to
// DS instruction count -> the cost is the 8-wave barrier/latency chain; this
// shrinks the synchronization scope to its minimum.
extern "C" __global__ __launch_bounds__(128, 1)
void crf_fb_kernel(const float* __restrict__ em,
                   const int* __restrict__ mask,
                   const int* __restrict__ tgt,
                   const float* __restrict__ trans,
                   const float* __restrict__ start,
                   const int* __restrict__ forb,
                   float* __restrict__ ef,      // [128][KK] forward exp-alpha
                   float* __restrict__ db,      // [128][KK] backward exp-beta
                   float* __restrict__ Mfb)     // [256] scales: fwd 0..127, bwd 128..255
{
    const int tid  = threadIdx.x;       // 0..127 == output state k
    const int k    = tid;
    const int w    = tid >> 6;
    const int lane = tid & 63;
    const bool fwdDir = (blockIdx.x < 2 * BB);
    const int c    = blockIdx.x & (2 * BB - 1);
    const int b    = c & (BB - 1);
    const bool sup = (c < BB);

    __shared__ __align__(16) float eLDS[2][KK];
    __shared__ __align__(8)  float wmLDS[2];
    __shared__ float redLDS[2];
    __shared__ int lenLDS;

    // ---- length ----
    if (tid == 0) lenLDS = 0;
    int ps = 0;
    const int4* __restrict__ mrow = (const int4*)(mask + (size_t)b * TT);
#pragma unroll
    for (int it = 0; it < 4; ++it) {
        const int4 m4 = mrow[tid + 128 * it];
        ps += m4.x + m4.y + m4.z + m4.w;
    }
    ps = waveSumI(ps);
    __syncthreads();                     // lenLDS zeroed before adds
    if (lane == 0) atomicAdd(&lenLDS, ps);

    const float st = start[k];
    const float* __restrict__ emrow = em + (size_t)b * TT * KK;
    const int* __restrict__ trow = tgt + (size_t)b * TT * KK;

    // ---- W in registers: fwd = column k of W; bwd = row k. 64 f32x2 pairs.
    f32x2 W2[64];
    if (fwdDir) {
#pragma unroll
        for (int j = 0; j < 64; ++j) {
            const int i0 = 2 * j, i1 = 2 * j + 1;
            const float w0 = forb[i0 * KK + k] ? 0.0f : __expf(trans[i0 * KK + k]);
            const float w1 = forb[i1 * KK + k] ? 0.0f : __expf(trans[i1 * KK + k]);
            W2[j] = (f32x2){w0, w1};
        }
    } else {
#pragma unroll
        for (int j = 0; j < 64; ++j) {
            const float w0 = forb[k * KK + 2 * j    ] ? 0.0f : __expf(trans[k * KK + 2 * j    ]);
            const float w1 = forb[k * KK + 2 * j + 1] ? 0.0f : __expf(trans[k * KK + 2 * j + 1]);
            W2[j] = (f32x2){w0, w1};
        }
    }
    __syncthreads();                     // lenLDS ready
    const int len = lenLDS;              // uniform, in [1024, 2048]
    const int mid = len >> 1;
    const int N   = fwdDir ? mid : (len - 1 - mid);   // serial steps (>=511)
    const int t0  = fwdDir ? 0 : (len - 1);

    // ---- init vector at t0: exact max renorm ----
    float v0 = emrow[(size_t)t0 * KK + k];
    if (sup && !trow[(size_t)t0 * KK + k]) v0 = -100000.0f;
    v0 += st;
    const float wm0 = waveMax(v0);
    if (lane == 0) redLDS[w] = wm0;
    __syncthreads();
    const float M0 = fmaxf(redLDS[0], redLDS[1]);
    double M = (double)M0;
    float eNew = __expf(v0 - M0);
    eLDS[0][k] = eNew;

    // iter n consumes bi[time]: fwd time=n; bwd time=len-1-n except the final
    // bwd iter which must NOT apply bi_mid (forward already owns it) -> bi:=0.
    auto loadBi = [&](int n) -> float {
        if (n > N || (!fwdDir && n == N)) return 0.0f;
        const int t = fwdDir ? n : (len - 1 - n);
        float e0 = emrow[(size_t)t * KK + k];
        if (sup) { if (!trow[(size_t)t * KK + k]) e0 = -100000.0f; }
        return e0 + st;
    };

    float biA = loadBi(1), biB = loadBi(2), biC = loadBi(3), biD = loadBi(4);
    lds_barrier();                       // publish eLDS[0]

#pragma unroll 4
    for (int n = 1; n <= N; ++n) {
        const int p = (n - 1) & 1;
        const float biN = loadBi(n + 4); // rides across lgkm-only barriers

        // block-renorm (proven cadence): measure at n%4==3 from the previous
        // step's eNew (scalar per lane -> wave DPP-max), apply at n%4==0.
        if ((n & 3) == 3) {
            const float u = waveMaxTo63(__logf(eNew));
            if (lane == 63) wmLDS[w] = u;
        }
        float r = 0.0f;
        if ((n & 3) == 0) {
            const float2 wmv = *(const float2*)wmLDS;  // uniform b64 broadcast
            r = fmaxf(wmv.x, wmv.y);
            M += (double)r;
        }
        const float f = __expf(biA - r);  // off critical path (needed after matvec)

        // full 128-input dot product per lane; e via uniform broadcast reads
        const float4* __restrict__ ev = (const float4*)eLDS[p];
        f32x2 a0 = {0.f,0.f}, a1 = {0.f,0.f}, a2 = {0.f,0.f}, a3 = {0.f,0.f};
#pragma unroll
        for (int j = 0; j < 32; j += 4) {
            const float4 E0 = ev[j], E1 = ev[j + 1], E2 = ev[j + 2], E3 = ev[j + 3];
            PKFMA(((f32x2){E0.x, E0.y}), W2[2 * j    ], a0);
            PKFMA(((f32x2){E0.z, E0.w}), W2[2 * j + 1], a1);
            PKFMA(((f32x2){E1.x, E1.y}), W2[2 * j + 2], a2);
            PKFMA(((f32x2){E1.z, E1.w}), W2[2 * j + 3], a3);
            PKFMA(((f32x2){E2.x, E2.y}), W2[2 * j + 4], a0);
            PKFMA(((f32x2){E2.z, E2.w}), W2[2 * j + 5], a1);
            PKFMA(((f32x2){E3.x, E3.y}), W2[2 * j + 6], a2);
            PKFMA(((f32x2){E3.z, E3.w}), W2[2 * j + 7], a3);
        }
        const f32x2 aa = (a0 + a1) + (a2 + a3);
        const float s = aa[0] + aa[1];

        eNew = s * f;
        eLDS[p ^ 1][k] = eNew;           // 1 ds_write_b32, conflict-free

        biA = biB; biB = biC; biC = biD; biD = biN;
        lds_barrier();                   // single barrier/step, only 2 waves
    }

    (fwdDir ? ef : db)[(size_t)c * KK + k] = eNew;
    if (tid == 0) Mfb[(fwdDir ? 0 : 2 * BB) + c] = (float)M;
}

// z[c] = Mf[c] + Mb[c] + log(dot(ef[c], db[c])); out[b] = z[b] - z[b+64]
extern "C" __global__ void crf_combine_kernel(const float* __restrict__ ef,
                                              const float* __restrict__ db,
                                              const float* __restrict__ Mfb,
                                              float* __restrict__ out)
{
    const int b = blockIdx.x;
    const int tid = threadIdx.x;         // 0..127 = state
    const int wv = tid >> 6, lane = tid & 63;
    __shared__ float red[2][2];
    __shared__ float z[2];
#pragma unroll
    for (int s = 0; s < 2; ++s) {
        const int c = b + s * BB;
        const float v = ef[(size_t)c * KK + tid] * db[(size_t)c * KK + tid];
        const float p = waveSum(v);
        if (lane == 0) red[s][wv] = p;
    }
    __syncthreads();
    if (tid < 2) {
        const int c = b + tid * BB;
        z[tid] = Mfb[c] + Mfb[2 * BB + c] + __logf(red[tid][0] + red[tid][1]);
    }
    __syncthreads();
    if (tid == 0) out[b] = z[0] - z[1];
}

// ---------------- fallback (R8, proven): used only if ws is too small -------
extern "C" __global__ __launch_bounds__(512)
__attribute__((amdgpu_waves_per_eu(2, 2)))
void crf_chain_kernel(const float* __restrict__ em, const int* __restrict__ mask,
                      const int* __restrict__ tgt, const float* __restrict__ trans,
                      const float* __restrict__ start, const int* __restrict__ forb,
                      float* __restrict__ zbuf)
{
    const int tid = threadIdx.x;
    const int k = tid >> 2, q = tid & 3, w = tid >> 6, lane = tid & 63;
    const int c = blockIdx.x, b = c & (BB - 1);
    const bool sup = (c < BB);
    __shared__ __align__(16) float eLDS[2][KK];
    __shared__ float wmLDS[8];
    __shared__ float redLDS[8];
    __shared__ int lenLDS;
    if (tid == 0) lenLDS = 0;
    const int4 m4 = ((const int4*)(mask + (size_t)b * TT))[tid];
    int ps = m4.x + m4.y + m4.z + m4.w;
    ps = waveSumI(ps);
    __syncthreads();
    if (lane == 0) atomicAdd(&lenLDS, ps);
    const float st = start[k];
    const float* __restrict__ emrow = em + (size_t)b * TT * KK;
    const int* __restrict__ trow = tgt + (size_t)b * TT * KK;
    const int ib = q * 32;
    f32x16 Wa, Wb;
#pragma unroll
    for (int j = 0; j < 16; ++j) {
        Wa[j] = forb[(ib + j     ) * KK + k] ? 0.0f : __expf(trans[(ib + j     ) * KK + k]);
        Wb[j] = forb[(ib + 16 + j) * KK + k] ? 0.0f : __expf(trans[(ib + 16 + j) * KK + k]);
    }
    float v0 = emrow[k];
    if (sup && !trow[k]) v0 = -100000.0f;
    v0 += st;
    const float wm0 = waveMax(v0);
    if (lane == 0) redLDS[w] = wm0;
    __syncthreads();
    const int len = lenLDS;
    float M0 = fmaxf(fmaxf(fmaxf(redLDS[0], redLDS[1]), fmaxf(redLDS[2], redLDS[3])),
                     fmaxf(fmaxf(redLDS[4], redLDS[5]), fmaxf(redLDS[6], redLDS[7])));
    double M = (double)M0;
    float eNew = __expf(v0 - M0);
    if (q == 0) eLDS[0][k] = eNew;
    auto bival = [&](int t) -> float {
        float e0 = emrow[(size_t)t * KK + k];
        if (sup) { if (!trow[(size_t)t * KK + k]) e0 = -100000.0f; }
        return e0 + st;
    };
    float biA = (len > 1) ? bival(1) : 0.0f;
    float biB = (len > 2) ? bival(2) : 0.0f;
    float biC = (len > 3) ? bival(3) : 0.0f;
    float biD = (len > 4) ? bival(4) : 0.0f;
    float sPrev = 1.0f, baPrev = 0.0f;
    lds_barrier();
#pragma unroll 4
    for (int t = 1; t < len; ++t) {
        const int p = (t - 1) & 1;
        const float biN = (t + 4 < len) ? bival(t + 4) : 0.0f;
        if ((t & 3) == 3) {
            const float u = __logf(sPrev) + baPrev;
            const float wmx = waveMaxFast(u);
            if (lane == 0) wmLDS[w] = wmx;
        }
        float r = 0.0f;
        if ((t & 3) == 0) {
            r = fmaxf(fmaxf(fmaxf(wmLDS[0], wmLDS[1]), fmaxf(wmLDS[2], wmLDS[3])),
                      fmaxf(fmaxf(wmLDS[4], wmLDS[5]), fmaxf(wmLDS[6], wmLDS[7])));
            M += (double)r;
        }
        const float ba = biA - r;
        const float f = __expf(ba);
        const float4* __restrict__ ev = (const float4*)eLDS[p] + q * 8;
        float s;
        MATVEC_QUARTER(Wa, Wb, ev, s)
        s = quadSum(s);
        eNew = s * f;
        if (q == 0) eLDS[p ^ 1][k] = eNew;
        sPrev = s; baPrev = ba;
        biA = biB; biB = biC; biC = biD; biD = biN;
        lds_barrier();
    }
    const float sm = waveSum((q == 0) ? eNew : 0.0f);
    if (lane == 0) redLDS[w] = sm;
    __syncthreads();
    if (tid == 0) {
        const float ss = ((redLDS[0] + redLDS[1]) + (redLDS[2] + redLDS[3]))
                       + ((redLDS[4] + redLDS[5]) + (redLDS[6] + redLDS[7]));
        zbuf[c] = (float)(M + (double)__logf(ss));
    }
}

extern "C" __global__ void crf_final_kernel(const float* __restrict__ z,
                                            float* __restrict__ out)
{
    const int b = threadIdx.x;
    out[b] = z[b] - z[b + BB];
}

extern "C" void kernel_launch(void* const* d_in, const int* in_sizes, int n_in,
                              void* d_out, int out_size, void* d_ws, size_t ws_size,
                              hipStream_t stream) {
    const float* em    = (const float*)d_in[0];
    const int*   mask  = (const int*)d_in[1];
    const int*   tgt   = (const int*)d_in[2];
    const float* trans = (const float*)d_in[3];
    const float* start = (const float*)d_in[4];
    const int*   forb  = (const int*)d_in[5];

    const size_t need = (size_t)(2 * 2 * BB * KK + 4 * BB) * sizeof(float); // 132 KB
    if (ws_size >= need) {
        float* ef  = (float*)d_ws;                       // [128][128]
        float* db  = ef + 2 * BB * KK;                   // [128][128]
        float* Mfb = db + 2 * BB * KK;                   // [256]
        crf_fb_kernel<<<4 * BB, 128, 0, stream>>>(em, mask, tgt, trans, start,
                                                  forb, ef, db, Mfb);
        crf_combine_kernel<<<BB, 128, 0, stream>>>(ef, db, Mfb, (float*)d_out);
    } else {
        float* zbuf = (float*)d_ws;
        crf_chain_kernel<<<2 * BB, 512, 0, stream>>>(em, mask, tgt, trans, start,
                                                     forb, zbuf);
        crf_final_kernel<<<1, BB, 0, stream>>>(zbuf, (float*)d_out);
    }
}

// Round 3
// 1099.965 us; speedup vs baseline: 1.0220x; 1.0139x over previous
//
#include <hip/hip_runtime.h>
#include <stdint.h>

#define BB 64
#define TT 2048
#define KK 128

typedef float f32x16 __attribute__((ext_vector_type(16)));
typedef float f32x2  __attribute__((ext_vector_type(2)));

__device__ __forceinline__ float waveMax(float v) {
#pragma unroll
    for (int off = 32; off; off >>= 1) v = fmaxf(v, __shfl_xor(v, off, 64));
    return v;
}
__device__ __forceinline__ float waveSum(float v) {
#pragma unroll
    for (int off = 32; off; off >>= 1) v += __shfl_xor(v, off, 64);
    return v;
}
__device__ __forceinline__ int waveSumI(int v) {
#pragma unroll
    for (int off = 32; off; off >>= 1) v += __shfl_xor(v, off, 64);
    return v;
}
// quad reduction via DPP quad_perm (VALU-speed; replaces 2 ds_bpermute)
__device__ __forceinline__ float quadSum(float s) {
    int x = __builtin_amdgcn_mov_dpp(__float_as_int(s), 0xB1, 0xf, 0xf, true); // xor1
    s += __int_as_float(x);
    x = __builtin_amdgcn_mov_dpp(__float_as_int(s), 0x4E, 0xf, 0xf, true);     // xor2
    s += __int_as_float(x);
    return s;
}
__device__ __forceinline__ float waveMaxFast(float v) {
    int x = __builtin_amdgcn_mov_dpp(__float_as_int(v), 0xB1, 0xf, 0xf, true);
    v = fmaxf(v, __int_as_float(x));
    x = __builtin_amdgcn_mov_dpp(__float_as_int(v), 0x4E, 0xf, 0xf, true);
    v = fmaxf(v, __int_as_float(x));
#pragma unroll
    for (int off = 4; off <= 32; off <<= 1) v = fmaxf(v, __shfl_xor(v, off, 64));
    return v;
}

// ---- DPP primitives (all-VALU, no DS pipe) ----
template<int C> __device__ __forceinline__ float dppMax(float v) {
    int x = __builtin_amdgcn_mov_dpp(__float_as_int(v), C, 0xf, 0xf, true);
    return fmaxf(v, __int_as_float(x));
}
// wave max; result valid in lanes 32..63 (write from lane 63). All-DPP.
__device__ __forceinline__ float waveMaxTo63(float v) {
    v = dppMax<0xB1>(v);
    v = dppMax<0x4E>(v);
    v = dppMax<0x124>(v);
    v = dppMax<0x128>(v);   // each 16-row now holds row-max replicated
    v = dppMax<0x142>(v);   // row_bcast15
    v = dppMax<0x143>(v);   // row_bcast31 -> lanes 32..63 = full max
    return v;
}

// lgkm-only barrier: LDS visibility without draining global prefetch (vmcnt).
__device__ __forceinline__ void lds_barrier() {
    asm volatile("s_waitcnt lgkmcnt(0)\n\ts_barrier" ::: "memory");
}

#define PKFMA(ep, wp, acc) acc = __builtin_elementwise_fma(ep, wp, acc)

#define MATVEC_QUARTER(Wa, Wb, ev, sOut) {                          \
    const float4 e0 = ev[0], e1 = ev[1], e2 = ev[2], e3 = ev[3];    \
    const float4 e4 = ev[4], e5 = ev[5], e6 = ev[6], e7 = ev[7];    \
    f32x2 a0 = {0.f,0.f}, a1 = {0.f,0.f}, a2 = {0.f,0.f}, a3 = {0.f,0.f}; \
    PKFMA(((f32x2){e0.x, e0.y}), ((f32x2){Wa[0],  Wa[1]}),  a0);    \
    PKFMA(((f32x2){e0.z, e0.w}), ((f32x2){Wa[2],  Wa[3]}),  a1);    \
    PKFMA(((f32x2){e1.x, e1.y}), ((f32x2){Wa[4],  Wa[5]}),  a2);    \
    PKFMA(((f32x2){e1.z, e1.w}), ((f32x2){Wa[6],  Wa[7]}),  a3);    \
    PKFMA(((f32x2){e2.x, e2.y}), ((f32x2){Wa[8],  Wa[9]}),  a0);    \
    PKFMA(((f32x2){e2.z, e2.w}), ((f32x2){Wa[10], Wa[11]}), a1);    \
    PKFMA(((f32x2){e3.x, e3.y}), ((f32x2){Wa[12], Wa[13]}), a2);    \
    PKFMA(((f32x2){e3.z, e3.w}), ((f32x2){Wa[14], Wa[15]}), a3);    \
    PKFMA(((f32x2){e4.x, e4.y}), ((f32x2){Wb[0],  Wb[1]}),  a0);    \
    PKFMA(((f32x2){e4.z, e4.w}), ((f32x2){Wb[2],  Wb[3]}),  a1);    \
    PKFMA(((f32x2){e5.x, e5.y}), ((f32x2){Wb[4],  Wb[5]}),  a2);    \
    PKFMA(((f32x2){e5.z, e5.w}), ((f32x2){Wb[6],  Wb[7]}),  a3);    \
    PKFMA(((f32x2){e6.x, e6.y}), ((f32x2){Wb[8],  Wb[9]}),  a0);    \
    PKFMA(((f32x2){e6.z, e6.w}), ((f32x2){Wb[10], Wb[11]}), a1);    \
    PKFMA(((f32x2){e7.x, e7.y}), ((f32x2){Wb[12], Wb[13]}), a2);    \
    PKFMA(((f32x2){e7.z, e7.w}), ((f32x2){Wb[14], Wb[15]}), a3);    \
    const f32x2 s2 = (a0 + a1) + (a2 + a3);                         \
    sOut = s2[0] + s2[1]; }

// Forward/backward meet-in-the-middle. R2 post-mortem: VGPR_Count=84 with a
// 128-float W operand per thread => W was SPILLED to scratch and re-streamed
// every step (64 KB/step/CU) -- the same was true (W=32 floats vs 40 VGPRs)
// for ALL earlier variants, which is why per-step cost looked "structural".
// THIS round's single change: amdgpu_waves_per_eu(1,1) so the allocator may
// use up to 512 VGPRs -> W2[64] (128 regs) stays resident, zero spill. We run
// 2 waves/block, 1 block/CU, so capping at 1 wave/SIMD costs nothing.
extern "C" __global__ __launch_bounds__(128, 1)
__attribute__((amdgpu_waves_per_eu(1, 1)))
void crf_fb_kernel(const float* __restrict__ em,
                   const int* __restrict__ mask,
                   const int* __restrict__ tgt,
                   const float* __restrict__ trans,
                   const float* __restrict__ start,
                   const int* __restrict__ forb,
                   float* __restrict__ ef,      // [128][KK] forward exp-alpha
                   float* __restrict__ db,      // [128][KK] backward exp-beta
                   float* __restrict__ Mfb)     // [256] scales: fwd 0..127, bwd 128..255
{
    const int tid  = threadIdx.x;       // 0..127 == output state k
    const int k    = tid;
    const int w    = tid >> 6;
    const int lane = tid & 63;
    const bool fwdDir = (blockIdx.x < 2 * BB);
    const int c    = blockIdx.x & (2 * BB - 1);
    const int b    = c & (BB - 1);
    const bool sup = (c < BB);

    __shared__ __align__(16) float eLDS[2][KK];
    __shared__ __align__(8)  float wmLDS[2];
    __shared__ float redLDS[2];
    __shared__ int lenLDS;

    // ---- length ----
    if (tid == 0) lenLDS = 0;
    int ps = 0;
    const int4* __restrict__ mrow = (const int4*)(mask + (size_t)b * TT);
#pragma unroll
    for (int it = 0; it < 4; ++it) {
        const int4 m4 = mrow[tid + 128 * it];
        ps += m4.x + m4.y + m4.z + m4.w;
    }
    ps = waveSumI(ps);
    __syncthreads();                     // lenLDS zeroed before adds
    if (lane == 0) atomicAdd(&lenLDS, ps);

    const float st = start[k];
    const float* __restrict__ emrow = em + (size_t)b * TT * KK;
    const int* __restrict__ trow = tgt + (size_t)b * TT * KK;

    // ---- W in registers: fwd = column k of W; bwd = row k. 64 f32x2 pairs.
    f32x2 W2[64];
    if (fwdDir) {
#pragma unroll
        for (int j = 0; j < 64; ++j) {
            const int i0 = 2 * j, i1 = 2 * j + 1;
            const float w0 = forb[i0 * KK + k] ? 0.0f : __expf(trans[i0 * KK + k]);
            const float w1 = forb[i1 * KK + k] ? 0.0f : __expf(trans[i1 * KK + k]);
            W2[j] = (f32x2){w0, w1};
        }
    } else {
#pragma unroll
        for (int j = 0; j < 64; ++j) {
            const float w0 = forb[k * KK + 2 * j    ] ? 0.0f : __expf(trans[k * KK + 2 * j    ]);
            const float w1 = forb[k * KK + 2 * j + 1] ? 0.0f : __expf(trans[k * KK + 2 * j + 1]);
            W2[j] = (f32x2){w0, w1};
        }
    }
    __syncthreads();                     // lenLDS ready
    const int len = lenLDS;              // uniform, in [1024, 2048]
    const int mid = len >> 1;
    const int N   = fwdDir ? mid : (len - 1 - mid);   // serial steps (>=511)
    const int t0  = fwdDir ? 0 : (len - 1);

    // ---- init vector at t0: exact max renorm ----
    float v0 = emrow[(size_t)t0 * KK + k];
    if (sup && !trow[(size_t)t0 * KK + k]) v0 = -100000.0f;
    v0 += st;
    const float wm0 = waveMax(v0);
    if (lane == 0) redLDS[w] = wm0;
    __syncthreads();
    const float M0 = fmaxf(redLDS[0], redLDS[1]);
    double M = (double)M0;
    float eNew = __expf(v0 - M0);
    eLDS[0][k] = eNew;

    // iter n consumes bi[time]: fwd time=n; bwd time=len-1-n except the final
    // bwd iter which must NOT apply bi_mid (forward already owns it) -> bi:=0.
    auto loadBi = [&](int n) -> float {
        if (n > N || (!fwdDir && n == N)) return 0.0f;
        const int t = fwdDir ? n : (len - 1 - n);
        float e0 = emrow[(size_t)t * KK + k];
        if (sup) { if (!trow[(size_t)t * KK + k]) e0 = -100000.0f; }
        return e0 + st;
    };

    float biA = loadBi(1), biB = loadBi(2), biC = loadBi(3), biD = loadBi(4);
    lds_barrier();                       // publish eLDS[0]

#pragma unroll 4
    for (int n = 1; n <= N; ++n) {
        const int p = (n - 1) & 1;
        const float biN = loadBi(n + 4); // rides across lgkm-only barriers

        // block-renorm (proven cadence): measure at n%4==3 from the previous
        // step's eNew (scalar per lane -> wave DPP-max), apply at n%4==0.
        if ((n & 3) == 3) {
            const float u = waveMaxTo63(__logf(eNew));
            if (lane == 63) wmLDS[w] = u;
        }
        float r = 0.0f;
        if ((n & 3) == 0) {
            const float2 wmv = *(const float2*)wmLDS;  // uniform b64 broadcast
            r = fmaxf(wmv.x, wmv.y);
            M += (double)r;
        }
        const float f = __expf(biA - r);  // off critical path (needed after matvec)

        // full 128-input dot product per lane; e via uniform broadcast reads
        const float4* __restrict__ ev = (const float4*)eLDS[p];
        f32x2 a0 = {0.f,0.f}, a1 = {0.f,0.f}, a2 = {0.f,0.f}, a3 = {0.f,0.f};
#pragma unroll
        for (int j = 0; j < 32; j += 4) {
            const float4 E0 = ev[j], E1 = ev[j + 1], E2 = ev[j + 2], E3 = ev[j + 3];
            PKFMA(((f32x2){E0.x, E0.y}), W2[2 * j    ], a0);
            PKFMA(((f32x2){E0.z, E0.w}), W2[2 * j + 1], a1);
            PKFMA(((f32x2){E1.x, E1.y}), W2[2 * j + 2], a2);
            PKFMA(((f32x2){E1.z, E1.w}), W2[2 * j + 3], a3);
            PKFMA(((f32x2){E2.x, E2.y}), W2[2 * j + 4], a0);
            PKFMA(((f32x2){E2.z, E2.w}), W2[2 * j + 5], a1);
            PKFMA(((f32x2){E3.x, E3.y}), W2[2 * j + 6], a2);
            PKFMA(((f32x2){E3.z, E3.w}), W2[2 * j + 7], a3);
        }
        const f32x2 aa = (a0 + a1) + (a2 + a3);
        const float s = aa[0] + aa[1];

        eNew = s * f;
        eLDS[p ^ 1][k] = eNew;           // 1 ds_write_b32, conflict-free

        biA = biB; biB = biC; biC = biD; biD = biN;
        lds_barrier();                   // single barrier/step, only 2 waves
    }

    (fwdDir ? ef : db)[(size_t)c * KK + k] = eNew;
    if (tid == 0) Mfb[(fwdDir ? 0 : 2 * BB) + c] = (float)M;
}

// z[c] = Mf[c] + Mb[c] + log(dot(ef[c], db[c])); out[b] = z[b] - z[b+64]
extern "C" __global__ void crf_combine_kernel(const float* __restrict__ ef,
                                              const float* __restrict__ db,
                                              const float* __restrict__ Mfb,
                                              float* __restrict__ out)
{
    const int b = blockIdx.x;
    const int tid = threadIdx.x;         // 0..127 = state
    const int wv = tid >> 6, lane = tid & 63;
    __shared__ float red[2][2];
    __shared__ float z[2];
#pragma unroll
    for (int s = 0; s < 2; ++s) {
        const int c = b + s * BB;
        const float v = ef[(size_t)c * KK + tid] * db[(size_t)c * KK + tid];
        const float p = waveSum(v);
        if (lane == 0) red[s][wv] = p;
    }
    __syncthreads();
    if (tid < 2) {
        const int c = b + tid * BB;
        z[tid] = Mfb[c] + Mfb[2 * BB + c] + __logf(red[tid][0] + red[tid][1]);
    }
    __syncthreads();
    if (tid == 0) out[b] = z[0] - z[1];
}

// ---------------- fallback (R8, proven): used only if ws is too small -------
extern "C" __global__ __launch_bounds__(512)
__attribute__((amdgpu_waves_per_eu(2, 2)))
void crf_chain_kernel(const float* __restrict__ em, const int* __restrict__ mask,
                      const int* __restrict__ tgt, const float* __restrict__ trans,
                      const float* __restrict__ start, const int* __restrict__ forb,
                      float* __restrict__ zbuf)
{
    const int tid = threadIdx.x;
    const int k = tid >> 2, q = tid & 3, w = tid >> 6, lane = tid & 63;
    const int c = blockIdx.x, b = c & (BB - 1);
    const bool sup = (c < BB);
    __shared__ __align__(16) float eLDS[2][KK];
    __shared__ float wmLDS[8];
    __shared__ float redLDS[8];
    __shared__ int lenLDS;
    if (tid == 0) lenLDS = 0;
    const int4 m4 = ((const int4*)(mask + (size_t)b * TT))[tid];
    int ps = m4.x + m4.y + m4.z + m4.w;
    ps = waveSumI(ps);
    __syncthreads();
    if (lane == 0) atomicAdd(&lenLDS, ps);
    const float st = start[k];
    const float* __restrict__ emrow = em + (size_t)b * TT * KK;
    const int* __restrict__ trow = tgt + (size_t)b * TT * KK;
    const int ib = q * 32;
    f32x16 Wa, Wb;
#pragma unroll
    for (int j = 0; j < 16; ++j) {
        Wa[j] = forb[(ib + j     ) * KK + k] ? 0.0f : __expf(trans[(ib + j     ) * KK + k]);
        Wb[j] = forb[(ib + 16 + j) * KK + k] ? 0.0f : __expf(trans[(ib + 16 + j) * KK + k]);
    }
    float v0 = emrow[k];
    if (sup && !trow[k]) v0 = -100000.0f;
    v0 += st;
    const float wm0 = waveMax(v0);
    if (lane == 0) redLDS[w] = wm0;
    __syncthreads();
    const int len = lenLDS;
    float M0 = fmaxf(fmaxf(fmaxf(redLDS[0], redLDS[1]), fmaxf(redLDS[2], redLDS[3])),
                     fmaxf(fmaxf(redLDS[4], redLDS[5]), fmaxf(redLDS[6], redLDS[7])));
    double M = (double)M0;
    float eNew = __expf(v0 - M0);
    if (q == 0) eLDS[0][k] = eNew;
    auto bival = [&](int t) -> float {
        float e0 = emrow[(size_t)t * KK + k];
        if (sup) { if (!trow[(size_t)t * KK + k]) e0 = -100000.0f; }
        return e0 + st;
    };
    float biA = (len > 1) ? bival(1) : 0.0f;
    float biB = (len > 2) ? bival(2) : 0.0f;
    float biC = (len > 3) ? bival(3) : 0.0f;
    float biD = (len > 4) ? bival(4) : 0.0f;
    float sPrev = 1.0f, baPrev = 0.0f;
    lds_barrier();
#pragma unroll 4
    for (int t = 1; t < len; ++t) {
        const int p = (t - 1) & 1;
        const float biN = (t + 4 < len) ? bival(t + 4) : 0.0f;
        if ((t & 3) == 3) {
            const float u = __logf(sPrev) + baPrev;
            const float wmx = waveMaxFast(u);
            if (lane == 0) wmLDS[w] = wmx;
        }
        float r = 0.0f;
        if ((t & 3) == 0) {
            r = fmaxf(fmaxf(fmaxf(wmLDS[0], wmLDS[1]), fmaxf(wmLDS[2], wmLDS[3])),
                      fmaxf(fmaxf(wmLDS[4], wmLDS[5]), fmaxf(wmLDS[6], wmLDS[7])));
            M += (double)r;
        }
        const float ba = biA - r;
        const float f = __expf(ba);
        const float4* __restrict__ ev = (const float4*)eLDS[p] + q * 8;
        float s;
        MATVEC_QUARTER(Wa, Wb, ev, s)
        s = quadSum(s);
        eNew = s * f;
        if (q == 0) eLDS[p ^ 1][k] = eNew;
        sPrev = s; baPrev = ba;
        biA = biB; biB = biC; biC = biD; biD = biN;
        lds_barrier();
    }
    const float sm = waveSum((q == 0) ? eNew : 0.0f);
    if (lane == 0) redLDS[w] = sm;
    __syncthreads();
    if (tid == 0) {
        const float ss = ((redLDS[0] + redLDS[1]) + (redLDS[2] + redLDS[3]))
                       + ((redLDS[4] + redLDS[5]) + (redLDS[6] + redLDS[7]));
        zbuf[c] = (float)(M + (double)__logf(ss));
    }
}

extern "C" __global__ void crf_final_kernel(const float* __restrict__ z,
                                            float* __restrict__ out)
{
    const int b = threadIdx.x;
    out[b] = z[b] - z[b + BB];
}

extern "C" void kernel_launch(void* const* d_in, const int* in_sizes, int n_in,
                              void* d_out, int out_size, void* d_ws, size_t ws_size,
                              hipStream_t stream) {
    const float* em    = (const float*)d_in[0];
    const int*   mask  = (const int*)d_in[1];
    const int*   tgt   = (const int*)d_in[2];
    const float* trans = (const float*)d_in[3];
    const float* start = (const float*)d_in[4];
    const int*   forb  = (const int*)d_in[5];

    const size_t need = (size_t)(2 * 2 * BB * KK + 4 * BB) * sizeof(float); // 132 KB
    if (ws_size >= need) {
        float* ef  = (float*)d_ws;                       // [128][128]
        float* db  = ef + 2 * BB * KK;                   // [128][128]
        float* Mfb = db + 2 * BB * KK;                   // [256]
        crf_fb_kernel<<<4 * BB, 128, 0, stream>>>(em, mask, tgt, trans, start,
                                                  forb, ef, db, Mfb);
        crf_combine_kernel<<<BB, 128, 0, stream>>>(ef, db, Mfb, (float*)d_out);
    } else {
        float* zbuf = (float*)d_ws;
        crf_chain_kernel<<<2 * BB, 512, 0, stream>>>(em, mask, tgt, trans, start,
                                                     forb, zbuf);
        crf_final_kernel<<<1, BB, 0, stream>>>(zbuf, (float*)d_out);
    }
}